// Round 3
// baseline (18.357 us; speedup 1.0000x reference)
//
#include <hip/hip_runtime.h>

#define EPS 1e-6f

// ---------------- Kernel 1: one wave per (b,k) -> handles near AND far rows ----------------
// BK = 2816 waves, 16 waves/block -> 176 blocks; each block writes ONE partial.
__global__ __launch_bounds__(1024) void traj_loss_partial_kernel(
    const float* __restrict__ anear,
    const float* __restrict__ afar,
    const int* __restrict__ na_idx,   // near_anchor_indexs (B,K)
    const int* __restrict__ fa_idx,   // far_anchor_indexs  (B,K)
    const int* __restrict__ ne_idx,   // near_indexs        (B,K)
    const int* __restrict__ fe_idx,   // far_indexs         (B,K)
    const float* __restrict__ ntgt,   // near_target (B*K)
    const float* __restrict__ ftgt,   // far_target  (B*K)
    float* __restrict__ partials,
    int B, int K)
{
    const int wave_g = (blockIdx.x * 1024 + threadIdx.x) >> 6;  // 0..BK-1
    const int lane   = threadIdx.x & 63;
    const int wid    = threadIdx.x >> 6;                        // 0..15
    const int BK     = B * K;

    float loss2 = 0.0f;
    if (wave_g < BK) {
        const int row = wave_g;        // = b*K + k
        const int b   = row / K;

        // 4 independent gathers (near pair + far pair) -> 2x ILP on latency chain
        const int sa = na_idx[row];
        const int sb = ne_idx[row];
        const int sc = fa_idx[row];
        const int sd = fe_idx[row];

        // layout (S, B, D=128): elem (s,b,d) at ((s*B)+b)*128 + d
        const float2* pa = (const float2*)(anear + ((size_t)sa * B + b) * 128);
        const float2* pb = (const float2*)(anear + ((size_t)sb * B + b) * 128);
        const float2* pc = (const float2*)(afar  + ((size_t)sc * B + b) * 128);
        const float2* pd = (const float2*)(afar  + ((size_t)sd * B + b) * 128);

        const float2 va = pa[lane];
        const float2 vb = pb[lane];
        const float2 vc = pc[lane];
        const float2 vd = pd[lane];

        const float dx = va.x - vb.x + EPS;
        const float dy = va.y - vb.y + EPS;
        float s1 = dx * dx + dy * dy;

        const float ex = vc.x - vd.x + EPS;
        const float ey = vc.y - vd.y + EPS;
        float s2 = ex * ex + ey * ey;

        #pragma unroll
        for (int off = 32; off > 0; off >>= 1) {
            s1 += __shfl_down(s1, off, 64);
            s2 += __shfl_down(s2, off, 64);
        }

        if (lane == 0) {
            const float l1 = __expf(-sqrtf(s1)) - ntgt[row];
            const float l2 = __expf(-sqrtf(s2)) - ftgt[row];
            loss2 = l1 * l1 + l2 * l2;
        }
    }

    __shared__ float wp[16];
    if (lane == 0) wp[wid] = loss2;
    __syncthreads();
    if (threadIdx.x == 0) {
        float s = 0.0f;
        #pragma unroll
        for (int i = 0; i < 16; ++i) s += wp[i];
        partials[blockIdx.x] = s;
    }
}

// ---------------- Kernel 2: reduce 176 partials -> out[0] (overwrite) ----------------
__global__ __launch_bounds__(256) void reduce_partials_kernel(
    const float* __restrict__ partials, float* __restrict__ out, int n)
{
    float s = (threadIdx.x < n) ? partials[threadIdx.x] : 0.0f;

    #pragma unroll
    for (int off = 32; off > 0; off >>= 1)
        s += __shfl_down(s, off, 64);

    __shared__ float wp[4];
    const int lane = threadIdx.x & 63;
    const int wid  = threadIdx.x >> 6;
    if (lane == 0) wp[wid] = s;
    __syncthreads();
    if (threadIdx.x == 0)
        out[0] = wp[0] + wp[1] + wp[2] + wp[3];
}

extern "C" void kernel_launch(void* const* d_in, const int* in_sizes, int n_in,
                              void* d_out, int out_size, void* d_ws, size_t ws_size,
                              hipStream_t stream) {
    const float* anear = (const float*)d_in[0];
    const float* afar  = (const float*)d_in[1];
    const int* na_idx  = (const int*)d_in[2];
    const int* fa_idx  = (const int*)d_in[3];
    const int* ne_idx  = (const int*)d_in[4];
    const int* fe_idx  = (const int*)d_in[5];
    const float* ntgt  = (const float*)d_in[6];
    const float* ftgt  = (const float*)d_in[7];
    float* out = (float*)d_out;
    float* partials = (float*)d_ws;

    const int B = 256;
    const int K = 11;
    const int BK = B * K;                       // 2816 waves
    const int wavesPerBlock = 16;               // 1024 threads
    const int grid = (BK + wavesPerBlock - 1) / wavesPerBlock;  // 176

    traj_loss_partial_kernel<<<grid, 1024, 0, stream>>>(anear, afar, na_idx, fa_idx,
                                                        ne_idx, fe_idx, ntgt, ftgt,
                                                        partials, B, K);
    reduce_partials_kernel<<<1, 256, 0, stream>>>(partials, out, grid);
}

// Round 4
// 12.065 us; speedup vs baseline: 1.5215x; 1.5215x over previous
//
#include <hip/hip_runtime.h>

#define EPS 1e-6f

// ---------------- Kernel 1: one wave per (b,k), both sides; 4 waves/block ----------------
// BK = 2816 waves, 4 waves/block -> 704 blocks; each block writes ONE partial.
__global__ __launch_bounds__(256) void traj_loss_partial_kernel(
    const float* __restrict__ anear,
    const float* __restrict__ afar,
    const int* __restrict__ na_idx,   // near_anchor_indexs (B,K)
    const int* __restrict__ fa_idx,   // far_anchor_indexs  (B,K)
    const int* __restrict__ ne_idx,   // near_indexs        (B,K)
    const int* __restrict__ fe_idx,   // far_indexs         (B,K)
    const float* __restrict__ ntgt,   // near_target (B*K)
    const float* __restrict__ ftgt,   // far_target  (B*K)
    float* __restrict__ partials,
    int B, int K)
{
    const int wave_g = (blockIdx.x * 256 + threadIdx.x) >> 6;  // 0..BK-1
    const int lane   = threadIdx.x & 63;
    const int wid    = threadIdx.x >> 6;                       // 0..3
    const int BK     = B * K;

    float loss2 = 0.0f;
    if (wave_g < BK) {
        const int row = wave_g;        // = b*K + k
        const int b   = row / K;

        // 4 independent gathers (near pair + far pair) -> 2x ILP on latency chain
        const int sa = na_idx[row];
        const int sb = ne_idx[row];
        const int sc = fa_idx[row];
        const int sd = fe_idx[row];

        // layout (S, B, D=128): elem (s,b,d) at ((s*B)+b)*128 + d
        const float2* pa = (const float2*)(anear + ((size_t)sa * B + b) * 128);
        const float2* pb = (const float2*)(anear + ((size_t)sb * B + b) * 128);
        const float2* pc = (const float2*)(afar  + ((size_t)sc * B + b) * 128);
        const float2* pd = (const float2*)(afar  + ((size_t)sd * B + b) * 128);

        const float2 va = pa[lane];
        const float2 vb = pb[lane];
        const float2 vc = pc[lane];
        const float2 vd = pd[lane];

        const float dx = va.x - vb.x + EPS;
        const float dy = va.y - vb.y + EPS;
        float s1 = dx * dx + dy * dy;

        const float ex = vc.x - vd.x + EPS;
        const float ey = vc.y - vd.y + EPS;
        float s2 = ex * ex + ey * ey;

        #pragma unroll
        for (int off = 32; off > 0; off >>= 1) {
            s1 += __shfl_down(s1, off, 64);
            s2 += __shfl_down(s2, off, 64);
        }

        if (lane == 0) {
            const float l1 = __expf(-sqrtf(s1)) - ntgt[row];
            const float l2 = __expf(-sqrtf(s2)) - ftgt[row];
            loss2 = l1 * l1 + l2 * l2;
        }
    }

    __shared__ float wp[4];
    if (lane == 0) wp[wid] = loss2;
    __syncthreads();
    if (threadIdx.x == 0)
        partials[blockIdx.x] = wp[0] + wp[1] + wp[2] + wp[3];
}

// ---------------- Kernel 2: reduce 704 partials -> out[0] (overwrite) ----------------
__global__ __launch_bounds__(256) void reduce_partials_kernel(
    const float* __restrict__ partials, float* __restrict__ out, int n)
{
    float s = 0.0f;
    for (int i = threadIdx.x; i < n; i += 256)
        s += partials[i];

    #pragma unroll
    for (int off = 32; off > 0; off >>= 1)
        s += __shfl_down(s, off, 64);

    __shared__ float wp[4];
    const int lane = threadIdx.x & 63;
    const int wid  = threadIdx.x >> 6;
    if (lane == 0) wp[wid] = s;
    __syncthreads();
    if (threadIdx.x == 0)
        out[0] = wp[0] + wp[1] + wp[2] + wp[3];
}

extern "C" void kernel_launch(void* const* d_in, const int* in_sizes, int n_in,
                              void* d_out, int out_size, void* d_ws, size_t ws_size,
                              hipStream_t stream) {
    const float* anear = (const float*)d_in[0];
    const float* afar  = (const float*)d_in[1];
    const int* na_idx  = (const int*)d_in[2];
    const int* fa_idx  = (const int*)d_in[3];
    const int* ne_idx  = (const int*)d_in[4];
    const int* fe_idx  = (const int*)d_in[5];
    const float* ntgt  = (const float*)d_in[6];
    const float* ftgt  = (const float*)d_in[7];
    float* out = (float*)d_out;
    float* partials = (float*)d_ws;

    const int B = 256;
    const int K = 11;
    const int BK = B * K;                        // 2816 waves
    const int wavesPerBlock = 4;                 // 256 threads
    const int grid = (BK + wavesPerBlock - 1) / wavesPerBlock;  // 704

    traj_loss_partial_kernel<<<grid, 256, 0, stream>>>(anear, afar, na_idx, fa_idx,
                                                       ne_idx, fe_idx, ntgt, ftgt,
                                                       partials, B, K);
    reduce_partials_kernel<<<1, 256, 0, stream>>>(partials, out, grid);
}